// Round 13
// baseline (301.527 us; speedup 1.0000x reference)
//
#include <hip/hip_runtime.h>

// GCN, bf16 Hs intermediate, FUSED layer boundaries.
// Build (3-phase): part (stripe-bin) -> part2 (sub-stripe bin, zeroes sums)
//   -> fill (LDS-tiled slot assign, coalesced cnt/csr flush).
// agg<FUSE>: gather + next-layer gemm epilogue (R12, -2 dispatches, -B1
//   roundtrip). agg<LAST>: pool fused, R13: 1024-THREAD blocks — R12's 3125
//   blocks x ~68 flush atomics = 213K device-scope atomics (~8-9us at the
//   measured ~25 ops/us wall); 782 blocks cuts it 4x. Tail is wave-aligned
//   (N%8=0) and guarded. Gather: 8 lanes/node, 8-deep batched uint4 + fmaf
//   masking (R11). R9 lesson: NO per-block __threadfence rendezvous.
// gemm1 R13: 64-row/2rx8c with NAMED scalar accs — old 2rx4c was
//   LDS-issue-bound (23.6cy ds_read vs 16cy FMA per k); 8 cols amortizes
//   (35.6 vs 32). R7 lesson: no acc ARRAYS (scratch spill); named scalars.
constexpr int N = 100000;
constexpr int E = 1250000;
constexpr int G = 64;
constexpr int K = 32;            // bucket cap; P(deg>32)*N ~ 0.1, exact ovf path
constexpr int OVF_CAP = 65536;
constexpr int STRIPES = 8;
constexpr int NPS = N / STRIPES;             // 12500 nodes per stripe
constexpr int SCAP = 164 * 1024;             // staging words per stripe
constexpr int PR = 1024;                     // edges binned per round
constexpr int PROUNDS = 2;
constexpr int PCHUNK = PR * PROUNDS;         // 2048 edges per part block
constexpr int PBLKS = (E + PCHUNK - 1) / PCHUNK;  // 611
constexpr int SUBN = 391;                    // nodes per fill block (391*32>=12500)
constexpr int SUBS = 32;                     // sub-stripes per stripe
constexpr int SCAP2 = 6 * 1024;              // words per sub-list (mean 4883 + 18 sigma)
constexpr int P2CAP = 240;                   // per-block sub-bin cap (mean 153 + 7 sigma)

typedef int v4i __attribute__((ext_vector_type(4)));

__device__ inline unsigned bf16pack(float a, float b) {  // RNE, low=a high=b
  unsigned ua = __float_as_uint(a);
  ua = (ua + 0x7FFF + ((ua >> 16) & 1)) >> 16;
  unsigned ub = __float_as_uint(b);
  ub = (ub + 0x7FFF + ((ub >> 16) & 1)) & 0xFFFF0000u;
  return ua | ub;
}

// ---- phase 1: single-pass partition into per-stripe staging ---------------
__global__ void part_kernel(const int* __restrict__ src, const int* __restrict__ dst,
                            unsigned* __restrict__ staged, int* __restrict__ cursors) {
  __shared__ unsigned bins[STRIPES][PR];
  __shared__ int bcnt[STRIPES];
  __shared__ int bbase[STRIPES];
  int tid = threadIdx.x;
  if (tid < STRIPES) bcnt[tid] = 0;
  __syncthreads();
  int base0 = blockIdx.x * PCHUNK;
  auto bin1 = [&](int s, int d) {
    int st = d / NPS;                       // magic-mul, d < 100000
    unsigned w = ((unsigned)s << 14) | (unsigned)(d - st * NPS);
    int p = atomicAdd(&bcnt[st], 1);
    bins[st][p] = w;
  };
#pragma unroll 1
  for (int r = 0; r < PROUNDS; r++) {
    int base = base0 + r * PR + tid * 4;
    if (base + 3 < E) {
      v4i s4 = __builtin_nontemporal_load((const v4i*)(src + base));
      v4i d4 = __builtin_nontemporal_load((const v4i*)(dst + base));
      bin1(s4.x, d4.x); bin1(s4.y, d4.y); bin1(s4.z, d4.z); bin1(s4.w, d4.w);
    } else {
      for (int j = 0; j < 4; j++)
        if (base + j < E) bin1(src[base + j], dst[base + j]);
    }
    __syncthreads();
    if (tid < STRIPES) bbase[tid] = atomicAdd(&cursors[tid], bcnt[tid]);
    __syncthreads();
#pragma unroll 1
    for (int b = 0; b < STRIPES; b++) {
      int c = bcnt[b];
      unsigned* out = staged + (size_t)b * SCAP + bbase[b];
      for (int k = tid; k < c; k += 256) out[k] = bins[b][k];
    }
    __syncthreads();
    if (tid < STRIPES) bcnt[tid] = 0;
    __syncthreads();
  }
}

// ---- phase 1b: re-bin each stripe list into 32 sub-stripe lists ------------
// Block 0 also zeroes sums/cnts (pool fused into agg-3 needs them clean).
__global__ void part2_kernel(const unsigned* __restrict__ staged, const int* __restrict__ cursors,
                             unsigned* __restrict__ staged2, int* __restrict__ cursors2,
                             float* __restrict__ sums) {
  __shared__ unsigned bins[SUBS][P2CAP];    // 30.7 KB
  __shared__ int bcnt[SUBS];
  __shared__ int bbase[SUBS];
  int tid = threadIdx.x;
  if (blockIdx.x == 0) {                    // zero sums[G*64] + cnts[G]
    for (int i = tid; i < G * 64 + G; i += 256) sums[i] = 0.f;
  }
  int s = blockIdx.x & (STRIPES - 1);       // stripe -> XCD heuristic (same as fill reader)
  int blk = blockIdx.x >> 3;                // 0..31: chunk of this stripe's list
  if (tid < SUBS) bcnt[tid] = 0;
  __syncthreads();
  int n = cursors[s];
  const unsigned* sbuf = staged + (size_t)s * SCAP;
  int chunk = (n + SUBS - 1) / SUBS;
  int lo2 = blk * chunk, hi2 = min(lo2 + chunk, n);
  for (int i = lo2 + tid; i < hi2; i += 256) {
    unsigned w = __builtin_nontemporal_load(sbuf + i);
    int local = (int)(w & 0x3FFFu);
    int b = local / SUBN;                   // 0..31, magic-mul
    int slot = atomicAdd(&bcnt[b], 1);
    if (slot < P2CAP) {
      bins[b][slot] = w;
    } else {                                // ~7-sigma fallback, still exact
      int q = atomicAdd(&cursors2[s * SUBS + b], 1);
      staged2[(size_t)(s * SUBS + b) * SCAP2 + q] = w;
    }
  }
  __syncthreads();
  if (tid < SUBS) bbase[tid] = atomicAdd(&cursors2[s * SUBS + tid], min(bcnt[tid], P2CAP));
  __syncthreads();
#pragma unroll 1
  for (int b = 0; b < SUBS; b++) {
    int c = min(bcnt[b], P2CAP);
    unsigned* out = staged2 + (size_t)(s * SUBS + b) * SCAP2 + bbase[b];
    for (int k = tid; k < c; k += 256) out[k] = bins[b][k];  // ~600B coalesced runs
  }
}

// ---- phase 2: LDS-tiled fill, one block per 391-node sub-stripe ------------
__global__ __launch_bounds__(512)
void fill_kernel(const unsigned* __restrict__ staged2, const int* __restrict__ cursors2,
                 int* __restrict__ cnt, int* __restrict__ csr,
                 int* __restrict__ ovf, int* __restrict__ ovf_cnt) {
  __shared__ int lcnt[SUBN];
  __shared__ int lcsr[SUBN * K];            // 48.9 KB
  int strp = blockIdx.x & (STRIPES - 1);    // stripe -> XCD heuristic, matches part2 writer
  int sub = blockIdx.x >> 3;                // 0..31
  int tid = threadIdx.x;
  for (int i = tid; i < SUBN; i += 512) lcnt[i] = 0;
  __syncthreads();
  int idx2 = strp * SUBS + sub;
  int n2 = cursors2[idx2];
  const unsigned* sbuf = staged2 + (size_t)idx2 * SCAP2;
  int lo = sub * SUBN;
  int nodes = min(SUBN, NPS - lo);          // 391, last sub: 379
  for (int i = tid; i < n2; i += 512) {
    unsigned w = sbuf[i];
    int local = (int)(w & 0x3FFFu);
    int ld = local - lo;                    // in [0,nodes) by construction
    int slot = atomicAdd(&lcnt[ld], 1);     // LDS atomic, in-CU
    int sr = (int)(w >> 14);
    if (slot < K) {
      lcsr[ld * K + slot] = sr;
    } else {
      int q = atomicAdd(ovf_cnt, 1);        // rare exact path
      if (q < OVF_CAP) { ovf[2 * q] = sr; ovf[2 * q + 1] = strp * NPS + local; }
    }
  }
  __syncthreads();
  int nb = strp * NPS + lo;
  for (int i = tid; i < nodes; i += 512) cnt[nb + i] = lcnt[i];
  uint4* dstp = (uint4*)(csr + (size_t)nb * K);       // nb*128B, 16B-aligned
  const uint4* srcp = (const uint4*)lcsr;
  int q4 = nodes * (K / 4);
  for (int i = tid; i < q4; i += 512) dstp[i] = srcp[i];  // full-line coalesced
}

// ---- Hs(bf16) = (X @ W) * dinv[row], 64 rows/block, 2r x 8c named accs -----
constexpr int XS_STRIDE = 68;
__global__ __launch_bounds__(256)
void gemm_premul_kernel(const float* __restrict__ X, const float* __restrict__ W,
                        const int* __restrict__ cnt, unsigned* __restrict__ Hs2) {
  __shared__ float Ws[64 * 64];             // 16 KB
  __shared__ float Xs[64 * XS_STRIDE];      // 17.4 KB
  int tid = threadIdx.x;
  const float4* W4 = (const float4*)W;
#pragma unroll
  for (int j = 0; j < 4; j++)
    ((float4*)Ws)[tid + j * 256] = W4[tid + j * 256];
  int row0 = blockIdx.x * 64;
  int nrows = min(64, N - row0);            // last block: 32
  int nidx = nrows * 16;
  const float4* X4 = (const float4*)(X + (size_t)row0 * 64);
#pragma unroll
  for (int j = 0; j < 4; j++) {
    int idx = tid + j * 256;
    if (idx < nidx) {
      int r = idx >> 4, q = idx & 15;
      *((float4*)&Xs[r * XS_STRIDE + q * 4]) = X4[idx];
    }
  }
  __syncthreads();
  int r = tid >> 3;                         // 0..31: rows r and r+32
  int cq = (tid & 7) * 2;                   // two float4s -> cols [(tid&7)*8, +8)
  float a0 = 0, a1 = 0, a2 = 0, a3 = 0, a4 = 0, a5 = 0, a6 = 0, a7 = 0;
  float a8 = 0, a9 = 0, a10 = 0, a11 = 0, a12 = 0, a13 = 0, a14 = 0, a15 = 0;
#pragma unroll
  for (int k = 0; k < 64; k++) {
    const float4* wr = (const float4*)(Ws + k * 64);
    float4 w0 = wr[cq], w1 = wr[cq + 1];
    float xa = Xs[r * XS_STRIDE + k];
    float xb = Xs[(r + 32) * XS_STRIDE + k];
    a0 = fmaf(xa, w0.x, a0);  a1 = fmaf(xa, w0.y, a1);
    a2 = fmaf(xa, w0.z, a2);  a3 = fmaf(xa, w0.w, a3);
    a4 = fmaf(xa, w1.x, a4);  a5 = fmaf(xa, w1.y, a5);
    a6 = fmaf(xa, w1.z, a6);  a7 = fmaf(xa, w1.w, a7);
    a8 = fmaf(xb, w0.x, a8);  a9 = fmaf(xb, w0.y, a9);
    a10 = fmaf(xb, w0.z, a10); a11 = fmaf(xb, w0.w, a11);
    a12 = fmaf(xb, w1.x, a12); a13 = fmaf(xb, w1.y, a13);
    a14 = fmaf(xb, w1.z, a14); a15 = fmaf(xb, w1.w, a15);
  }
  int ra = row0 + r;                        // always < N (tail has nrows=32, r<32)
  float da = rsqrtf((float)cnt[ra] + 1.0f);
  uint4 p;
  p.x = bf16pack(a0 * da, a1 * da);  p.y = bf16pack(a2 * da, a3 * da);
  p.z = bf16pack(a4 * da, a5 * da);  p.w = bf16pack(a6 * da, a7 * da);
  ((uint4*)Hs2)[(size_t)ra * 8 + (tid & 7)] = p;
  int rb = ra + 32;
  if (rb - row0 < nrows) {
    float db = rsqrtf((float)cnt[rb] + 1.0f);
    uint4 q2;
    q2.x = bf16pack(a8 * db, a9 * db);   q2.y = bf16pack(a10 * db, a11 * db);
    q2.z = bf16pack(a12 * db, a13 * db); q2.w = bf16pack(a14 * db, a15 * db);
    ((uint4*)Hs2)[(size_t)rb * 8 + (tid & 7)] = q2;
  }
}

// ---- pull aggregation: 8 lanes/node, 8-deep batched gathers ----------------
// LAST=false: 256 thr, fused next-layer gemm epilogue -> HsN (bf16, premul).
// LAST=true : 1024 thr (128 nodes/block, 4x fewer flush atomics), pool fused.
template <bool LAST>
__global__ __launch_bounds__(LAST ? 1024 : 256)
void agg_kernel(const unsigned* __restrict__ Hs2, const int* __restrict__ cnt,
                const int* __restrict__ csr, const int* __restrict__ ovf,
                const int* __restrict__ ovf_cnt, const float* __restrict__ b,
                const float* __restrict__ Wn, unsigned* __restrict__ HsN,
                const int* __restrict__ batch,
                float* __restrict__ sums, float* __restrict__ cnts) {
  constexpr int NPB = LAST ? 128 : 32;        // nodes per block
  __shared__ float smem[64 * 64 + 32 * 68];   // 25.1 KB: WLds+rowLds | gsum/gcnt
  __shared__ int gmin_s;
  float* WLds = smem;                          // [64][64]   (FUSE)
  float (*rowLds)[68] = (float(*)[68])(smem + 4096);  // [32][68] (FUSE)
  float (*gsum)[64] = (float(*)[64])smem;      // [4][64]    (LAST)
  float* gcnt = smem + 256;                    // [4]        (LAST)
  int tid = threadIdx.x;
  if constexpr (!LAST) {
    const float4* W4 = (const float4*)Wn;      // issue early; hides under gathers
#pragma unroll
    for (int j = 0; j < 4; j++)
      ((float4*)WLds)[tid + j * 256] = W4[tid + j * 256];
  } else {
    if (tid < 260) smem[tid] = 0.f;            // gsum + gcnt
    if (tid == 0) gmin_s = batch[blockIdx.x * NPB];
    __syncthreads();
  }
  int lane = tid & 63;
  int i = lane & 7;                         // owns dims [8i, 8i+8)
  int gb = lane & 56;                       // group base lane
  int node = blockIdx.x * NPB + (tid >> 3); // 8 lanes/node
  bool wvalid = node < N;                   // wave-uniform (N % 8 == 0)
  int nodeC = min(node, N - 1);             // clamped for tail-block loads
  int c = cnt[nodeC];
  int mg = wvalid ? min(c, K) : 0;
  // preload this node's csr bucket: lane i holds slots i, 8+i, 16+i, 24+i
  int sv0 = csr[nodeC * K + i];
  int sv1 = csr[nodeC * K + 8 + i];
  int sv2 = csr[nodeC * K + 16 + i];
  int sv3 = csr[nodeC * K + 24 + i];
  // wave-wide max degree (lockstep loop bound; per-group fmaf masking inside)
  int mm = mg;
  mm = max(mm, __shfl_xor(mm, 8));
  mm = max(mm, __shfl_xor(mm, 16));
  mm = max(mm, __shfl_xor(mm, 32));
  const uint4* H4 = (const uint4*)Hs2;
  float acc0 = 0, acc1 = 0, acc2 = 0, acc3 = 0, acc4 = 0, acc5 = 0, acc6 = 0, acc7 = 0;
  auto accm = [&](uint4 h, float m) {
    acc0 = fmaf(m, __uint_as_float(h.x << 16), acc0);
    acc1 = fmaf(m, __uint_as_float(h.x & 0xFFFF0000u), acc1);
    acc2 = fmaf(m, __uint_as_float(h.y << 16), acc2);
    acc3 = fmaf(m, __uint_as_float(h.y & 0xFFFF0000u), acc3);
    acc4 = fmaf(m, __uint_as_float(h.z << 16), acc4);
    acc5 = fmaf(m, __uint_as_float(h.z & 0xFFFF0000u), acc5);
    acc6 = fmaf(m, __uint_as_float(h.w << 16), acc6);
    acc7 = fmaf(m, __uint_as_float(h.w & 0xFFFF0000u), acc7);
  };
  // 8 loads issued back-to-back into named regs (8 in flight), then consumed.
  auto edge8 = [&](int sv, int eb) {
    int t0 = __shfl(sv, gb + 0), t1 = __shfl(sv, gb + 1);
    int t2 = __shfl(sv, gb + 2), t3 = __shfl(sv, gb + 3);
    int t4 = __shfl(sv, gb + 4), t5 = __shfl(sv, gb + 5);
    int t6 = __shfl(sv, gb + 6), t7 = __shfl(sv, gb + 7);
    uint4 h0 = H4[(size_t)(eb + 0 < mg ? t0 : nodeC) * 8 + i];
    uint4 h1 = H4[(size_t)(eb + 1 < mg ? t1 : nodeC) * 8 + i];
    uint4 h2 = H4[(size_t)(eb + 2 < mg ? t2 : nodeC) * 8 + i];
    uint4 h3 = H4[(size_t)(eb + 3 < mg ? t3 : nodeC) * 8 + i];
    uint4 h4 = H4[(size_t)(eb + 4 < mg ? t4 : nodeC) * 8 + i];
    uint4 h5 = H4[(size_t)(eb + 5 < mg ? t5 : nodeC) * 8 + i];
    uint4 h6 = H4[(size_t)(eb + 6 < mg ? t6 : nodeC) * 8 + i];
    uint4 h7 = H4[(size_t)(eb + 7 < mg ? t7 : nodeC) * 8 + i];
    accm(h0, eb + 0 < mg ? 1.f : 0.f);
    accm(h1, eb + 1 < mg ? 1.f : 0.f);
    accm(h2, eb + 2 < mg ? 1.f : 0.f);
    accm(h3, eb + 3 < mg ? 1.f : 0.f);
    accm(h4, eb + 4 < mg ? 1.f : 0.f);
    accm(h5, eb + 5 < mg ? 1.f : 0.f);
    accm(h6, eb + 6 < mg ? 1.f : 0.f);
    accm(h7, eb + 7 < mg ? 1.f : 0.f);
  };
  if (mm > 0)  edge8(sv0, 0);
  if (mm > 8)  edge8(sv1, 8);
  if (mm > 16) edge8(sv2, 16);
  if (mm > 24) edge8(sv3, 24);
  int on = min(*ovf_cnt, OVF_CAP);
  for (int j = 0; j < on; j++) {            // exact rare path (deg > K), on ~ 0
    int dd = ovf[2 * j + 1];                // wave-broadcast load
    if (dd == node) accm(H4[(size_t)ovf[2 * j] * 8 + i], 1.f);
  }
  // node output (relu'd, bias'd); no cross-lane reduce needed
  uint4 hs = H4[(size_t)nodeC * 8 + i];     // self row
  float di = rsqrtf((float)c + 1.0f);
  const float4* b4 = (const float4*)b;
  float4 blo = b4[2 * i], bhi = b4[2 * i + 1];
  float4 o0, o1;
  o0.x = fmaxf(di * (acc0 + __uint_as_float(hs.x << 16)) + blo.x, 0.f);
  o0.y = fmaxf(di * (acc1 + __uint_as_float(hs.x & 0xFFFF0000u)) + blo.y, 0.f);
  o0.z = fmaxf(di * (acc2 + __uint_as_float(hs.y << 16)) + blo.z, 0.f);
  o0.w = fmaxf(di * (acc3 + __uint_as_float(hs.y & 0xFFFF0000u)) + blo.w, 0.f);
  o1.x = fmaxf(di * (acc4 + __uint_as_float(hs.z << 16)) + bhi.x, 0.f);
  o1.y = fmaxf(di * (acc5 + __uint_as_float(hs.z & 0xFFFF0000u)) + bhi.y, 0.f);
  o1.z = fmaxf(di * (acc6 + __uint_as_float(hs.w << 16)) + bhi.z, 0.f);
  o1.w = fmaxf(di * (acc7 + __uint_as_float(hs.w & 0xFFFF0000u)) + bhi.w, 0.f);
  if constexpr (!LAST) {
    // ---- fused next-layer gemm: stage rows, barrier, 32x64 @ 64x64 --------
    int n32 = tid >> 3;
    *(float4*)&rowLds[n32][8 * i] = o0;
    *(float4*)&rowLds[n32][8 * i + 4] = o1;
    __syncthreads();                         // covers WLds + rowLds writes
    int r = tid >> 3;                        // same node-row this thread owns
    int cq = (tid & 7) * 2;                  // float4 col-pair within W row
    float a0 = 0, a1 = 0, a2 = 0, a3 = 0, a4 = 0, a5 = 0, a6 = 0, a7 = 0;
#pragma unroll
    for (int k = 0; k < 64; k++) {
      float xv = rowLds[r][k];
      const float4* wr = (const float4*)(WLds + k * 64);
      float4 w0 = wr[cq], w1 = wr[cq + 1];
      a0 = fmaf(xv, w0.x, a0); a1 = fmaf(xv, w0.y, a1);
      a2 = fmaf(xv, w0.z, a2); a3 = fmaf(xv, w0.w, a3);
      a4 = fmaf(xv, w1.x, a4); a5 = fmaf(xv, w1.y, a5);
      a6 = fmaf(xv, w1.z, a6); a7 = fmaf(xv, w1.w, a7);
    }
    uint4 p;                                 // premul dinv[row] (same di), pack bf16
    p.x = bf16pack(a0 * di, a1 * di);
    p.y = bf16pack(a2 * di, a3 * di);
    p.z = bf16pack(a4 * di, a5 * di);
    p.w = bf16pack(a6 * di, a7 * di);
    ((uint4*)HsN)[(size_t)node * 8 + (tid & 7)] = p;   // coalesced 128B/row
  } else {
    if (wvalid) {
      int g = batch[node];
      int ref = __shfl(g, i);               // graph of the wave's first node
      if (__all(g == ref)) {
        // FAST: whole wave same graph — xor-reduce 8 nodes, group 0 flushes.
        float v0 = o0.x, v1 = o0.y, v2 = o0.z, v3 = o0.w;
        float v4 = o1.x, v5 = o1.y, v6 = o1.z, v7 = o1.w;
#pragma unroll
        for (int off = 8; off < 64; off <<= 1) {
          v0 += __shfl_xor(v0, off); v1 += __shfl_xor(v1, off);
          v2 += __shfl_xor(v2, off); v3 += __shfl_xor(v3, off);
          v4 += __shfl_xor(v4, off); v5 += __shfl_xor(v5, off);
          v6 += __shfl_xor(v6, off); v7 += __shfl_xor(v7, off);
        }
        if (gb == 0) {                      // group 0 only: conflict-free LDS adds
          int s = ref - gmin_s;             // uniform, in [0,4)
          atomicAdd(&gsum[s][8 * i + 0], v0); atomicAdd(&gsum[s][8 * i + 1], v1);
          atomicAdd(&gsum[s][8 * i + 2], v2); atomicAdd(&gsum[s][8 * i + 3], v3);
          atomicAdd(&gsum[s][8 * i + 4], v4); atomicAdd(&gsum[s][8 * i + 5], v5);
          atomicAdd(&gsum[s][8 * i + 6], v6); atomicAdd(&gsum[s][8 * i + 7], v7);
          if (i == 0) atomicAdd(&gcnt[s], 8.f);
        }
      } else {
        // SLOW: graph boundary inside wave (~6% of waves) — per-node adds.
        int s = g - gmin_s;
        if ((unsigned)s < 4u) {
          atomicAdd(&gsum[s][8 * i + 0], o0.x); atomicAdd(&gsum[s][8 * i + 1], o0.y);
          atomicAdd(&gsum[s][8 * i + 2], o0.z); atomicAdd(&gsum[s][8 * i + 3], o0.w);
          atomicAdd(&gsum[s][8 * i + 4], o1.x); atomicAdd(&gsum[s][8 * i + 5], o1.y);
          atomicAdd(&gsum[s][8 * i + 6], o1.z); atomicAdd(&gsum[s][8 * i + 7], o1.w);
          if (i == 0) atomicAdd(&gcnt[s], 1.f);
        } else {                            // out-of-window (never for sorted batch)
          atomicAdd(&sums[g * 64 + 8 * i + 0], o0.x); atomicAdd(&sums[g * 64 + 8 * i + 1], o0.y);
          atomicAdd(&sums[g * 64 + 8 * i + 2], o0.z); atomicAdd(&sums[g * 64 + 8 * i + 3], o0.w);
          atomicAdd(&sums[g * 64 + 8 * i + 4], o1.x); atomicAdd(&sums[g * 64 + 8 * i + 5], o1.y);
          atomicAdd(&sums[g * 64 + 8 * i + 6], o1.z); atomicAdd(&sums[g * 64 + 8 * i + 7], o1.w);
          if (i == 0) atomicAdd(&cnts[g], 1.f);
        }
      }
    }
    __syncthreads();
    if (tid < 256) {                        // guarded flush: ~1-2 slots/block live
      int s2 = tid >> 6, d = tid & 63;
      if (gcnt[s2] > 0.f) {
        atomicAdd(&sums[(gmin_s + s2) * 64 + d], gsum[s2][d]);
        if (d == 0) atomicAdd(&cnts[gmin_s + s2], gcnt[s2]);
      }
    }
  }
}

// ---- classifier ------------------------------------------------------------
__global__ void classifier_kernel(const float* __restrict__ sums, const float* __restrict__ cnts,
                                  const float* __restrict__ Wc1, const float* __restrict__ bc1,
                                  const float* __restrict__ Wc2, const float* __restrict__ bc2,
                                  float* __restrict__ out) {
  __shared__ float pooled[64 * 64];
  __shared__ float z[64 * 32];
  int tid = threadIdx.x;
  for (int idx = tid; idx < 64 * 64; idx += 256) {
    int g = idx >> 6;
    pooled[idx] = sums[idx] / fmaxf(cnts[g], 1.0f);
  }
  __syncthreads();
  for (int idx = tid; idx < 64 * 32; idx += 256) {
    int g = idx >> 5, j = idx & 31;
    float acc = bc1[j];
#pragma unroll
    for (int c = 0; c < 64; c++) acc += pooled[g * 64 + c] * Wc1[c * 32 + j];
    z[idx] = fmaxf(acc, 0.f);
  }
  __syncthreads();
  for (int idx = tid; idx < 128; idx += 256) {
    int g = idx >> 1, k = idx & 1;
    float acc = bc2[k];
#pragma unroll
    for (int j = 0; j < 32; j++) acc += z[g * 32 + j] * Wc2[j * 2 + k];
    out[idx] = acc;
  }
}

// ---- launch ----------------------------------------------------------------
extern "C" void kernel_launch(void* const* d_in, const int* in_sizes, int n_in,
                              void* d_out, int out_size, void* d_ws, size_t ws_size,
                              hipStream_t stream) {
  const float* x   = (const float*)d_in[0];
  const float* W1  = (const float*)d_in[1];
  const float* b1  = (const float*)d_in[2];
  const float* W2  = (const float*)d_in[3];
  const float* b2  = (const float*)d_in[4];
  const float* W3  = (const float*)d_in[5];
  const float* b3  = (const float*)d_in[6];
  const float* Wc1 = (const float*)d_in[7];
  const float* bc1 = (const float*)d_in[8];
  const float* Wc2 = (const float*)d_in[9];
  const float* bc2 = (const float*)d_in[10];
  const int* ei    = (const int*)d_in[11];
  const int* batch = (const int*)d_in[12];
  const int* src  = ei;
  const int* dstp = ei + E;

  char* ws = (char*)d_ws;
  size_t off = 0;
  auto alloc = [&](size_t bytes) {
    char* p = ws + off;
    off += (bytes + 255) & ~size_t(255);
    return p;
  };
  int*      cnt  = (int*)alloc((size_t)(N + 512) * 4);
  int*      csr  = (int*)alloc((size_t)N * K * 4);          // 12.8 MB
  int*      ovf  = (int*)alloc((size_t)OVF_CAP * 2 * 4);
  unsigned* HsA  = (unsigned*)alloc((size_t)N * 64 * 2);    // bf16, layer ping
  unsigned* HsB  = (unsigned*)alloc((size_t)N * 64 * 2);    // bf16, layer pong
  float*    B1   = (float*)alloc((size_t)N * 64 * 4);       // build staging only
  float*    sums = (float*)alloc((size_t)(G * 64 + G) * 4);
  float*    cnts = sums + G * 64;
  int*      ovf_cnt  = cnt + N;
  int*      cursors  = cnt + N + 16;       // 8 ints, own line
  int*      cursors2 = cnt + N + 64;       // 256 ints
  unsigned* staged  = (unsigned*)B1;       // 5.25 MB (dead after part2)
  unsigned* staged2 = (unsigned*)B1 + (size_t)STRIPES * SCAP;  // 6.29 MB (dead after fill)

  // ovf_cnt/cursors/cursors2 zeroed here; sums/cnts zeroed in part2.
  hipMemsetAsync(cnt + N, 0, 512 * 4, stream);

  part_kernel<<<PBLKS, 256, 0, stream>>>(src, dstp, staged, cursors);
  part2_kernel<<<STRIPES * SUBS, 256, 0, stream>>>(staged, cursors, staged2, cursors2, sums);
  fill_kernel<<<STRIPES * SUBS, 512, 0, stream>>>(staged2, cursors2, cnt, csr, ovf, ovf_cnt);

  gemm_premul_kernel<<<(N + 63) / 64, 256, 0, stream>>>(x, W1, cnt, HsA);
  // layer 1: gather HsA, fuse gemm2 -> HsB
  agg_kernel<false><<<N / 32, 256, 0, stream>>>(HsA, cnt, csr, ovf, ovf_cnt, b1,
                                                W2, HsB, batch, sums, cnts);
  // layer 2: gather HsB, fuse gemm3 -> HsA
  agg_kernel<false><<<N / 32, 256, 0, stream>>>(HsB, cnt, csr, ovf, ovf_cnt, b2,
                                                W3, HsA, batch, sums, cnts);
  // layer 3: gather HsA, pool fused (1024-thread blocks, 128 nodes each)
  agg_kernel<true><<<(N + 127) / 128, 1024, 0, stream>>>(HsA, cnt, csr, ovf, ovf_cnt, b3,
                                                         W1, HsB, batch, sums, cnts);

  classifier_kernel<<<1, 256, 0, stream>>>(sums, cnts, Wc1, bc1, Wc2, bc2, (float*)d_out);
}

// Round 14
// 251.280 us; speedup vs baseline: 1.2000x; 1.2000x over previous
//
#include <hip/hip_runtime.h>

// GCN, bf16 Hs intermediate, FUSED layer boundaries.
// Build (3-phase): part (stripe-bin) -> part2 (sub-stripe bin, zeroes sums)
//   -> fill (LDS-tiled slot assign, coalesced cnt/csr flush).
// agg<FUSE>: gather + next-layer gemm epilogue (R12, -2 dispatches, -B1
//   roundtrip). agg<LAST>: pool fused, 1024-thr blocks (R13-proven: 4x fewer
//   flush atomics, ~-10us). Gather: 8 lanes/node, 8-deep batched uint4 +
//   fmaf masking (R11). R9 lesson: NO per-block __threadfence rendezvous.
// gemm1: R6-proven 32-row/2-acc. GEMM WIDENING IS A DEAD END ON THIS SHAPE:
//   R7 4x4 float4-array -> scratch spill (772us); R13 2rx8c named scalars ->
//   VGPR=256 cap, occ 9%, 73us. The unroll64 x (accs+temps) product IS the
//   register budget; 2 float4 accs is the sweet spot (14us).
constexpr int N = 100000;
constexpr int E = 1250000;
constexpr int G = 64;
constexpr int K = 32;            // bucket cap; P(deg>32)*N ~ 0.1, exact ovf path
constexpr int OVF_CAP = 65536;
constexpr int STRIPES = 8;
constexpr int NPS = N / STRIPES;             // 12500 nodes per stripe
constexpr int SCAP = 164 * 1024;             // staging words per stripe
constexpr int PR = 1024;                     // edges binned per round
constexpr int PROUNDS = 2;
constexpr int PCHUNK = PR * PROUNDS;         // 2048 edges per part block
constexpr int PBLKS = (E + PCHUNK - 1) / PCHUNK;  // 611
constexpr int SUBN = 391;                    // nodes per fill block (391*32>=12500)
constexpr int SUBS = 32;                     // sub-stripes per stripe
constexpr int SCAP2 = 6 * 1024;              // words per sub-list (mean 4883 + 18 sigma)
constexpr int P2CAP = 240;                   // per-block sub-bin cap (mean 153 + 7 sigma)

typedef int v4i __attribute__((ext_vector_type(4)));

__device__ inline unsigned bf16pack(float a, float b) {  // RNE, low=a high=b
  unsigned ua = __float_as_uint(a);
  ua = (ua + 0x7FFF + ((ua >> 16) & 1)) >> 16;
  unsigned ub = __float_as_uint(b);
  ub = (ub + 0x7FFF + ((ub >> 16) & 1)) & 0xFFFF0000u;
  return ua | ub;
}

// ---- phase 1: single-pass partition into per-stripe staging ---------------
__global__ void part_kernel(const int* __restrict__ src, const int* __restrict__ dst,
                            unsigned* __restrict__ staged, int* __restrict__ cursors) {
  __shared__ unsigned bins[STRIPES][PR];
  __shared__ int bcnt[STRIPES];
  __shared__ int bbase[STRIPES];
  int tid = threadIdx.x;
  if (tid < STRIPES) bcnt[tid] = 0;
  __syncthreads();
  int base0 = blockIdx.x * PCHUNK;
  auto bin1 = [&](int s, int d) {
    int st = d / NPS;                       // magic-mul, d < 100000
    unsigned w = ((unsigned)s << 14) | (unsigned)(d - st * NPS);
    int p = atomicAdd(&bcnt[st], 1);
    bins[st][p] = w;
  };
#pragma unroll 1
  for (int r = 0; r < PROUNDS; r++) {
    int base = base0 + r * PR + tid * 4;
    if (base + 3 < E) {
      v4i s4 = __builtin_nontemporal_load((const v4i*)(src + base));
      v4i d4 = __builtin_nontemporal_load((const v4i*)(dst + base));
      bin1(s4.x, d4.x); bin1(s4.y, d4.y); bin1(s4.z, d4.z); bin1(s4.w, d4.w);
    } else {
      for (int j = 0; j < 4; j++)
        if (base + j < E) bin1(src[base + j], dst[base + j]);
    }
    __syncthreads();
    if (tid < STRIPES) bbase[tid] = atomicAdd(&cursors[tid], bcnt[tid]);
    __syncthreads();
#pragma unroll 1
    for (int b = 0; b < STRIPES; b++) {
      int c = bcnt[b];
      unsigned* out = staged + (size_t)b * SCAP + bbase[b];
      for (int k = tid; k < c; k += 256) out[k] = bins[b][k];
    }
    __syncthreads();
    if (tid < STRIPES) bcnt[tid] = 0;
    __syncthreads();
  }
}

// ---- phase 1b: re-bin each stripe list into 32 sub-stripe lists ------------
// Block 0 also zeroes sums/cnts (pool fused into agg-3 needs them clean).
__global__ void part2_kernel(const unsigned* __restrict__ staged, const int* __restrict__ cursors,
                             unsigned* __restrict__ staged2, int* __restrict__ cursors2,
                             float* __restrict__ sums) {
  __shared__ unsigned bins[SUBS][P2CAP];    // 30.7 KB
  __shared__ int bcnt[SUBS];
  __shared__ int bbase[SUBS];
  int tid = threadIdx.x;
  if (blockIdx.x == 0) {                    // zero sums[G*64] + cnts[G]
    for (int i = tid; i < G * 64 + G; i += 256) sums[i] = 0.f;
  }
  int s = blockIdx.x & (STRIPES - 1);       // stripe -> XCD heuristic (same as fill reader)
  int blk = blockIdx.x >> 3;                // 0..31: chunk of this stripe's list
  if (tid < SUBS) bcnt[tid] = 0;
  __syncthreads();
  int n = cursors[s];
  const unsigned* sbuf = staged + (size_t)s * SCAP;
  int chunk = (n + SUBS - 1) / SUBS;
  int lo2 = blk * chunk, hi2 = min(lo2 + chunk, n);
  for (int i = lo2 + tid; i < hi2; i += 256) {
    unsigned w = __builtin_nontemporal_load(sbuf + i);
    int local = (int)(w & 0x3FFFu);
    int b = local / SUBN;                   // 0..31, magic-mul
    int slot = atomicAdd(&bcnt[b], 1);
    if (slot < P2CAP) {
      bins[b][slot] = w;
    } else {                                // ~7-sigma fallback, still exact
      int q = atomicAdd(&cursors2[s * SUBS + b], 1);
      staged2[(size_t)(s * SUBS + b) * SCAP2 + q] = w;
    }
  }
  __syncthreads();
  if (tid < SUBS) bbase[tid] = atomicAdd(&cursors2[s * SUBS + tid], min(bcnt[tid], P2CAP));
  __syncthreads();
#pragma unroll 1
  for (int b = 0; b < SUBS; b++) {
    int c = min(bcnt[b], P2CAP);
    unsigned* out = staged2 + (size_t)(s * SUBS + b) * SCAP2 + bbase[b];
    for (int k = tid; k < c; k += 256) out[k] = bins[b][k];  // ~600B coalesced runs
  }
}

// ---- phase 2: LDS-tiled fill, one block per 391-node sub-stripe ------------
__global__ __launch_bounds__(512)
void fill_kernel(const unsigned* __restrict__ staged2, const int* __restrict__ cursors2,
                 int* __restrict__ cnt, int* __restrict__ csr,
                 int* __restrict__ ovf, int* __restrict__ ovf_cnt) {
  __shared__ int lcnt[SUBN];
  __shared__ int lcsr[SUBN * K];            // 48.9 KB
  int strp = blockIdx.x & (STRIPES - 1);    // stripe -> XCD heuristic, matches part2 writer
  int sub = blockIdx.x >> 3;                // 0..31
  int tid = threadIdx.x;
  for (int i = tid; i < SUBN; i += 512) lcnt[i] = 0;
  __syncthreads();
  int idx2 = strp * SUBS + sub;
  int n2 = cursors2[idx2];
  const unsigned* sbuf = staged2 + (size_t)idx2 * SCAP2;
  int lo = sub * SUBN;
  int nodes = min(SUBN, NPS - lo);          // 391, last sub: 379
  for (int i = tid; i < n2; i += 512) {
    unsigned w = sbuf[i];
    int local = (int)(w & 0x3FFFu);
    int ld = local - lo;                    // in [0,nodes) by construction
    int slot = atomicAdd(&lcnt[ld], 1);     // LDS atomic, in-CU
    int sr = (int)(w >> 14);
    if (slot < K) {
      lcsr[ld * K + slot] = sr;
    } else {
      int q = atomicAdd(ovf_cnt, 1);        // rare exact path
      if (q < OVF_CAP) { ovf[2 * q] = sr; ovf[2 * q + 1] = strp * NPS + local; }
    }
  }
  __syncthreads();
  int nb = strp * NPS + lo;
  for (int i = tid; i < nodes; i += 512) cnt[nb + i] = lcnt[i];
  uint4* dstp = (uint4*)(csr + (size_t)nb * K);       // nb*128B, 16B-aligned
  const uint4* srcp = (const uint4*)lcsr;
  int q4 = nodes * (K / 4);
  for (int i = tid; i < q4; i += 512) dstp[i] = srcp[i];  // full-line coalesced
}

// ---- Hs(bf16) = (X @ W) * dinv[row], 32 rows/block (R6-proven) -------------
constexpr int XS_STRIDE = 68;
__global__ void gemm_premul_kernel(const float* __restrict__ X, const float* __restrict__ W,
                                   const int* __restrict__ cnt, unsigned* __restrict__ Hs2) {
  __shared__ float Ws[64 * 64];
  __shared__ float Xs[32 * XS_STRIDE];
  int tid = threadIdx.x;
  const float4* W4 = (const float4*)W;
#pragma unroll
  for (int j = 0; j < 4; j++)
    ((float4*)Ws)[tid + j * 256] = W4[tid + j * 256];
  int row0 = blockIdx.x * 32;
  const float4* X4 = (const float4*)(X + row0 * 64);
#pragma unroll
  for (int j = 0; j < 2; j++) {
    int idx = tid + j * 256;
    int r = idx >> 4, q = idx & 15;
    *((float4*)&Xs[r * XS_STRIDE + q * 4]) = X4[idx];
  }
  __syncthreads();
  int r0 = tid >> 4;
  int c = (tid & 15) * 4;
  float4 acc0 = {0, 0, 0, 0}, acc1 = {0, 0, 0, 0};
#pragma unroll
  for (int k = 0; k < 64; k++) {
    float4 w = *((const float4*)&Ws[k * 64 + c]);
    float xa = Xs[r0 * XS_STRIDE + k];
    float xb = Xs[(r0 + 16) * XS_STRIDE + k];
    acc0.x += xa * w.x; acc0.y += xa * w.y; acc0.z += xa * w.z; acc0.w += xa * w.w;
    acc1.x += xb * w.x; acc1.y += xb * w.y; acc1.z += xb * w.z; acc1.w += xb * w.w;
  }
  int ra = row0 + r0, rb = ra + 16;
  float da = rsqrtf((float)cnt[ra] + 1.0f);
  float db = rsqrtf((float)cnt[rb] + 1.0f);
  uint2 pa = make_uint2(bf16pack(acc0.x * da, acc0.y * da), bf16pack(acc0.z * da, acc0.w * da));
  uint2 pb = make_uint2(bf16pack(acc1.x * db, acc1.y * db), bf16pack(acc1.z * db, acc1.w * db));
  ((uint2*)Hs2)[ra * 16 + (tid & 15)] = pa;
  ((uint2*)Hs2)[rb * 16 + (tid & 15)] = pb;
}

// ---- pull aggregation: 8 lanes/node, 8-deep batched gathers ----------------
// LAST=false: 256 thr, fused next-layer gemm epilogue -> HsN (bf16, premul).
// LAST=true : 1024 thr (128 nodes/block, 4x fewer flush atomics), pool fused.
template <bool LAST>
__global__ __launch_bounds__(LAST ? 1024 : 256)
void agg_kernel(const unsigned* __restrict__ Hs2, const int* __restrict__ cnt,
                const int* __restrict__ csr, const int* __restrict__ ovf,
                const int* __restrict__ ovf_cnt, const float* __restrict__ b,
                const float* __restrict__ Wn, unsigned* __restrict__ HsN,
                const int* __restrict__ batch,
                float* __restrict__ sums, float* __restrict__ cnts) {
  constexpr int NPB = LAST ? 128 : 32;        // nodes per block
  __shared__ float smem[64 * 64 + 32 * 68];   // 25.1 KB: WLds+rowLds | gsum/gcnt
  __shared__ int gmin_s;
  float* WLds = smem;                          // [64][64]   (FUSE)
  float (*rowLds)[68] = (float(*)[68])(smem + 4096);  // [32][68] (FUSE)
  float (*gsum)[64] = (float(*)[64])smem;      // [4][64]    (LAST)
  float* gcnt = smem + 256;                    // [4]        (LAST)
  int tid = threadIdx.x;
  if constexpr (!LAST) {
    const float4* W4 = (const float4*)Wn;      // issue early; hides under gathers
#pragma unroll
    for (int j = 0; j < 4; j++)
      ((float4*)WLds)[tid + j * 256] = W4[tid + j * 256];
  } else {
    if (tid < 260) smem[tid] = 0.f;            // gsum + gcnt
    if (tid == 0) gmin_s = batch[blockIdx.x * NPB];
    __syncthreads();
  }
  int lane = tid & 63;
  int i = lane & 7;                         // owns dims [8i, 8i+8)
  int gb = lane & 56;                       // group base lane
  int node = blockIdx.x * NPB + (tid >> 3); // 8 lanes/node
  bool wvalid = node < N;                   // wave-uniform (N % 8 == 0)
  int nodeC = min(node, N - 1);             // clamped for tail-block loads
  int c = cnt[nodeC];
  int mg = wvalid ? min(c, K) : 0;
  // preload this node's csr bucket: lane i holds slots i, 8+i, 16+i, 24+i
  int sv0 = csr[nodeC * K + i];
  int sv1 = csr[nodeC * K + 8 + i];
  int sv2 = csr[nodeC * K + 16 + i];
  int sv3 = csr[nodeC * K + 24 + i];
  // wave-wide max degree (lockstep loop bound; per-group fmaf masking inside)
  int mm = mg;
  mm = max(mm, __shfl_xor(mm, 8));
  mm = max(mm, __shfl_xor(mm, 16));
  mm = max(mm, __shfl_xor(mm, 32));
  const uint4* H4 = (const uint4*)Hs2;
  float acc0 = 0, acc1 = 0, acc2 = 0, acc3 = 0, acc4 = 0, acc5 = 0, acc6 = 0, acc7 = 0;
  auto accm = [&](uint4 h, float m) {
    acc0 = fmaf(m, __uint_as_float(h.x << 16), acc0);
    acc1 = fmaf(m, __uint_as_float(h.x & 0xFFFF0000u), acc1);
    acc2 = fmaf(m, __uint_as_float(h.y << 16), acc2);
    acc3 = fmaf(m, __uint_as_float(h.y & 0xFFFF0000u), acc3);
    acc4 = fmaf(m, __uint_as_float(h.z << 16), acc4);
    acc5 = fmaf(m, __uint_as_float(h.z & 0xFFFF0000u), acc5);
    acc6 = fmaf(m, __uint_as_float(h.w << 16), acc6);
    acc7 = fmaf(m, __uint_as_float(h.w & 0xFFFF0000u), acc7);
  };
  // 8 loads issued back-to-back into named regs (8 in flight), then consumed.
  auto edge8 = [&](int sv, int eb) {
    int t0 = __shfl(sv, gb + 0), t1 = __shfl(sv, gb + 1);
    int t2 = __shfl(sv, gb + 2), t3 = __shfl(sv, gb + 3);
    int t4 = __shfl(sv, gb + 4), t5 = __shfl(sv, gb + 5);
    int t6 = __shfl(sv, gb + 6), t7 = __shfl(sv, gb + 7);
    uint4 h0 = H4[(size_t)(eb + 0 < mg ? t0 : nodeC) * 8 + i];
    uint4 h1 = H4[(size_t)(eb + 1 < mg ? t1 : nodeC) * 8 + i];
    uint4 h2 = H4[(size_t)(eb + 2 < mg ? t2 : nodeC) * 8 + i];
    uint4 h3 = H4[(size_t)(eb + 3 < mg ? t3 : nodeC) * 8 + i];
    uint4 h4 = H4[(size_t)(eb + 4 < mg ? t4 : nodeC) * 8 + i];
    uint4 h5 = H4[(size_t)(eb + 5 < mg ? t5 : nodeC) * 8 + i];
    uint4 h6 = H4[(size_t)(eb + 6 < mg ? t6 : nodeC) * 8 + i];
    uint4 h7 = H4[(size_t)(eb + 7 < mg ? t7 : nodeC) * 8 + i];
    accm(h0, eb + 0 < mg ? 1.f : 0.f);
    accm(h1, eb + 1 < mg ? 1.f : 0.f);
    accm(h2, eb + 2 < mg ? 1.f : 0.f);
    accm(h3, eb + 3 < mg ? 1.f : 0.f);
    accm(h4, eb + 4 < mg ? 1.f : 0.f);
    accm(h5, eb + 5 < mg ? 1.f : 0.f);
    accm(h6, eb + 6 < mg ? 1.f : 0.f);
    accm(h7, eb + 7 < mg ? 1.f : 0.f);
  };
  if (mm > 0)  edge8(sv0, 0);
  if (mm > 8)  edge8(sv1, 8);
  if (mm > 16) edge8(sv2, 16);
  if (mm > 24) edge8(sv3, 24);
  int on = min(*ovf_cnt, OVF_CAP);
  for (int j = 0; j < on; j++) {            // exact rare path (deg > K), on ~ 0
    int dd = ovf[2 * j + 1];                // wave-broadcast load
    if (dd == node) accm(H4[(size_t)ovf[2 * j] * 8 + i], 1.f);
  }
  // node output (relu'd, bias'd); no cross-lane reduce needed
  uint4 hs = H4[(size_t)nodeC * 8 + i];     // self row
  float di = rsqrtf((float)c + 1.0f);
  const float4* b4 = (const float4*)b;
  float4 blo = b4[2 * i], bhi = b4[2 * i + 1];
  float4 o0, o1;
  o0.x = fmaxf(di * (acc0 + __uint_as_float(hs.x << 16)) + blo.x, 0.f);
  o0.y = fmaxf(di * (acc1 + __uint_as_float(hs.x & 0xFFFF0000u)) + blo.y, 0.f);
  o0.z = fmaxf(di * (acc2 + __uint_as_float(hs.y << 16)) + blo.z, 0.f);
  o0.w = fmaxf(di * (acc3 + __uint_as_float(hs.y & 0xFFFF0000u)) + blo.w, 0.f);
  o1.x = fmaxf(di * (acc4 + __uint_as_float(hs.z << 16)) + bhi.x, 0.f);
  o1.y = fmaxf(di * (acc5 + __uint_as_float(hs.z & 0xFFFF0000u)) + bhi.y, 0.f);
  o1.z = fmaxf(di * (acc6 + __uint_as_float(hs.w << 16)) + bhi.z, 0.f);
  o1.w = fmaxf(di * (acc7 + __uint_as_float(hs.w & 0xFFFF0000u)) + bhi.w, 0.f);
  if constexpr (!LAST) {
    // ---- fused next-layer gemm: stage rows, barrier, 32x64 @ 64x64 --------
    int n32 = tid >> 3;
    *(float4*)&rowLds[n32][8 * i] = o0;
    *(float4*)&rowLds[n32][8 * i + 4] = o1;
    __syncthreads();                         // covers WLds + rowLds writes
    int r = tid >> 3;                        // same node-row this thread owns
    int cq = (tid & 7) * 2;                  // float4 col-pair within W row
    float a0 = 0, a1 = 0, a2 = 0, a3 = 0, a4 = 0, a5 = 0, a6 = 0, a7 = 0;
#pragma unroll
    for (int k = 0; k < 64; k++) {
      float xv = rowLds[r][k];
      const float4* wr = (const float4*)(WLds + k * 64);
      float4 w0 = wr[cq], w1 = wr[cq + 1];
      a0 = fmaf(xv, w0.x, a0); a1 = fmaf(xv, w0.y, a1);
      a2 = fmaf(xv, w0.z, a2); a3 = fmaf(xv, w0.w, a3);
      a4 = fmaf(xv, w1.x, a4); a5 = fmaf(xv, w1.y, a5);
      a6 = fmaf(xv, w1.z, a6); a7 = fmaf(xv, w1.w, a7);
    }
    uint4 p;                                 // premul dinv[row] (same di), pack bf16
    p.x = bf16pack(a0 * di, a1 * di);
    p.y = bf16pack(a2 * di, a3 * di);
    p.z = bf16pack(a4 * di, a5 * di);
    p.w = bf16pack(a6 * di, a7 * di);
    ((uint4*)HsN)[(size_t)node * 8 + (tid & 7)] = p;   // coalesced 128B/row
  } else {
    if (wvalid) {
      int g = batch[node];
      int ref = __shfl(g, i);               // graph of the wave's first node
      if (__all(g == ref)) {
        // FAST: whole wave same graph — xor-reduce 8 nodes, group 0 flushes.
        float v0 = o0.x, v1 = o0.y, v2 = o0.z, v3 = o0.w;
        float v4 = o1.x, v5 = o1.y, v6 = o1.z, v7 = o1.w;
#pragma unroll
        for (int off = 8; off < 64; off <<= 1) {
          v0 += __shfl_xor(v0, off); v1 += __shfl_xor(v1, off);
          v2 += __shfl_xor(v2, off); v3 += __shfl_xor(v3, off);
          v4 += __shfl_xor(v4, off); v5 += __shfl_xor(v5, off);
          v6 += __shfl_xor(v6, off); v7 += __shfl_xor(v7, off);
        }
        if (gb == 0) {                      // group 0 only: conflict-free LDS adds
          int s = ref - gmin_s;             // uniform, in [0,4)
          atomicAdd(&gsum[s][8 * i + 0], v0); atomicAdd(&gsum[s][8 * i + 1], v1);
          atomicAdd(&gsum[s][8 * i + 2], v2); atomicAdd(&gsum[s][8 * i + 3], v3);
          atomicAdd(&gsum[s][8 * i + 4], v4); atomicAdd(&gsum[s][8 * i + 5], v5);
          atomicAdd(&gsum[s][8 * i + 6], v6); atomicAdd(&gsum[s][8 * i + 7], v7);
          if (i == 0) atomicAdd(&gcnt[s], 8.f);
        }
      } else {
        // SLOW: graph boundary inside wave (~6% of waves) — per-node adds.
        int s = g - gmin_s;
        if ((unsigned)s < 4u) {
          atomicAdd(&gsum[s][8 * i + 0], o0.x); atomicAdd(&gsum[s][8 * i + 1], o0.y);
          atomicAdd(&gsum[s][8 * i + 2], o0.z); atomicAdd(&gsum[s][8 * i + 3], o0.w);
          atomicAdd(&gsum[s][8 * i + 4], o1.x); atomicAdd(&gsum[s][8 * i + 5], o1.y);
          atomicAdd(&gsum[s][8 * i + 6], o1.z); atomicAdd(&gsum[s][8 * i + 7], o1.w);
          if (i == 0) atomicAdd(&gcnt[s], 1.f);
        } else {                            // out-of-window (never for sorted batch)
          atomicAdd(&sums[g * 64 + 8 * i + 0], o0.x); atomicAdd(&sums[g * 64 + 8 * i + 1], o0.y);
          atomicAdd(&sums[g * 64 + 8 * i + 2], o0.z); atomicAdd(&sums[g * 64 + 8 * i + 3], o0.w);
          atomicAdd(&sums[g * 64 + 8 * i + 4], o1.x); atomicAdd(&sums[g * 64 + 8 * i + 5], o1.y);
          atomicAdd(&sums[g * 64 + 8 * i + 6], o1.z); atomicAdd(&sums[g * 64 + 8 * i + 7], o1.w);
          if (i == 0) atomicAdd(&cnts[g], 1.f);
        }
      }
    }
    __syncthreads();
    if (tid < 256) {                        // guarded flush: ~1-2 slots/block live
      int s2 = tid >> 6, d = tid & 63;
      if (gcnt[s2] > 0.f) {
        atomicAdd(&sums[(gmin_s + s2) * 64 + d], gsum[s2][d]);
        if (d == 0) atomicAdd(&cnts[gmin_s + s2], gcnt[s2]);
      }
    }
  }
}

// ---- classifier ------------------------------------------------------------
__global__ void classifier_kernel(const float* __restrict__ sums, const float* __restrict__ cnts,
                                  const float* __restrict__ Wc1, const float* __restrict__ bc1,
                                  const float* __restrict__ Wc2, const float* __restrict__ bc2,
                                  float* __restrict__ out) {
  __shared__ float pooled[64 * 64];
  __shared__ float z[64 * 32];
  int tid = threadIdx.x;
  for (int idx = tid; idx < 64 * 64; idx += 256) {
    int g = idx >> 6;
    pooled[idx] = sums[idx] / fmaxf(cnts[g], 1.0f);
  }
  __syncthreads();
  for (int idx = tid; idx < 64 * 32; idx += 256) {
    int g = idx >> 5, j = idx & 31;
    float acc = bc1[j];
#pragma unroll
    for (int c = 0; c < 64; c++) acc += pooled[g * 64 + c] * Wc1[c * 32 + j];
    z[idx] = fmaxf(acc, 0.f);
  }
  __syncthreads();
  for (int idx = tid; idx < 128; idx += 256) {
    int g = idx >> 1, k = idx & 1;
    float acc = bc2[k];
#pragma unroll
    for (int j = 0; j < 32; j++) acc += z[g * 32 + j] * Wc2[j * 2 + k];
    out[idx] = acc;
  }
}

// ---- launch ----------------------------------------------------------------
extern "C" void kernel_launch(void* const* d_in, const int* in_sizes, int n_in,
                              void* d_out, int out_size, void* d_ws, size_t ws_size,
                              hipStream_t stream) {
  const float* x   = (const float*)d_in[0];
  const float* W1  = (const float*)d_in[1];
  const float* b1  = (const float*)d_in[2];
  const float* W2  = (const float*)d_in[3];
  const float* b2  = (const float*)d_in[4];
  const float* W3  = (const float*)d_in[5];
  const float* b3  = (const float*)d_in[6];
  const float* Wc1 = (const float*)d_in[7];
  const float* bc1 = (const float*)d_in[8];
  const float* Wc2 = (const float*)d_in[9];
  const float* bc2 = (const float*)d_in[10];
  const int* ei    = (const int*)d_in[11];
  const int* batch = (const int*)d_in[12];
  const int* src  = ei;
  const int* dstp = ei + E;

  char* ws = (char*)d_ws;
  size_t off = 0;
  auto alloc = [&](size_t bytes) {
    char* p = ws + off;
    off += (bytes + 255) & ~size_t(255);
    return p;
  };
  int*      cnt  = (int*)alloc((size_t)(N + 512) * 4);
  int*      csr  = (int*)alloc((size_t)N * K * 4);          // 12.8 MB
  int*      ovf  = (int*)alloc((size_t)OVF_CAP * 2 * 4);
  unsigned* HsA  = (unsigned*)alloc((size_t)N * 64 * 2);    // bf16, layer ping
  unsigned* HsB  = (unsigned*)alloc((size_t)N * 64 * 2);    // bf16, layer pong
  float*    B1   = (float*)alloc((size_t)N * 64 * 4);       // build staging only
  float*    sums = (float*)alloc((size_t)(G * 64 + G) * 4);
  float*    cnts = sums + G * 64;
  int*      ovf_cnt  = cnt + N;
  int*      cursors  = cnt + N + 16;       // 8 ints, own line
  int*      cursors2 = cnt + N + 64;       // 256 ints
  unsigned* staged  = (unsigned*)B1;       // 5.25 MB (dead after part2)
  unsigned* staged2 = (unsigned*)B1 + (size_t)STRIPES * SCAP;  // 6.29 MB (dead after fill)

  // ovf_cnt/cursors/cursors2 zeroed here; sums/cnts zeroed in part2.
  hipMemsetAsync(cnt + N, 0, 512 * 4, stream);

  part_kernel<<<PBLKS, 256, 0, stream>>>(src, dstp, staged, cursors);
  part2_kernel<<<STRIPES * SUBS, 256, 0, stream>>>(staged, cursors, staged2, cursors2, sums);
  fill_kernel<<<STRIPES * SUBS, 512, 0, stream>>>(staged2, cursors2, cnt, csr, ovf, ovf_cnt);

  gemm_premul_kernel<<<N / 32, 256, 0, stream>>>(x, W1, cnt, HsA);
  // layer 1: gather HsA, fuse gemm2 -> HsB
  agg_kernel<false><<<N / 32, 256, 0, stream>>>(HsA, cnt, csr, ovf, ovf_cnt, b1,
                                                W2, HsB, batch, sums, cnts);
  // layer 2: gather HsB, fuse gemm3 -> HsA
  agg_kernel<false><<<N / 32, 256, 0, stream>>>(HsB, cnt, csr, ovf, ovf_cnt, b2,
                                                W3, HsA, batch, sums, cnts);
  // layer 3: gather HsA, pool fused (1024-thread blocks, 128 nodes each)
  agg_kernel<true><<<(N + 127) / 128, 1024, 0, stream>>>(HsA, cnt, csr, ovf, ovf_cnt, b3,
                                                         W1, HsB, batch, sums, cnts);

  classifier_kernel<<<1, 256, 0, stream>>>(sums, cnts, Wc1, bc1, Wc2, bc2, (float*)d_out);
}